// Round 4
// baseline (181.008 us; speedup 1.0000x reference)
//
#include <hip/hip_runtime.h>
#include <hip/hip_cooperative_groups.h>

namespace cg = cooperative_groups;

// B=32, C=3, IMG=256, N=65536, K=49152, JMAX=16384
#define NTOT 65536
#define CCH 3
#define BB 32
#define KK 49152
#define JMAXV 16384
#define A_FWHT 6144          // virtual blocks doing lo-FWHT
#define A_TOTAL 6400         // + 256 table-build virtual blocks
#define B_TILES 1024         // hi-FWHT/scatter tiles
#define GRID 512

struct F3 { float x, y, z; };

__device__ __forceinline__ void bfly(float& a, float& b) {
    float s = a + b, d = a - b; a = s; b = d;
}

// masks 1,2: DPP quad_perm (VALU pipe, not LDS)
template<int MASK>
__device__ __forceinline__ float bfly_dpp(float w, int lane) {
    constexpr int ctrl = (MASK == 1) ? 0xB1 : 0x4E;  // [1,0,3,2] / [2,3,0,1]
    float p = __uint_as_float((unsigned)__builtin_amdgcn_update_dpp(
        0, (int)__float_as_uint(w), ctrl, 0xF, 0xF, true));
    return (lane & MASK) ? p - w : w + p;
}

// masks 4,8: ds_swizzle via shfl_xor
template<int MASK>
__device__ __forceinline__ float bfly_swz(float w, int lane) {
    float p = __shfl_xor(w, MASK);
    return (lane & MASK) ? p - w : w + p;
}

// mask 16: permlane16_swap (VALU)
__device__ __forceinline__ float bfly_pl16(float w, int lane) {
#if __has_builtin(__builtin_amdgcn_permlane16_swap)
    unsigned u = __float_as_uint(w);
    auto r = __builtin_amdgcn_permlane16_swap(u, u, false, false);
    float a = __uint_as_float(r[0]), b = __uint_as_float(r[1]);
    return (lane & 16) ? a - b : a + b;
#else
    return bfly_swz<16>(w, lane);
#endif
}

// mask 32: permlane32_swap (VALU)
__device__ __forceinline__ float bfly_pl32(float w, int lane) {
#if __has_builtin(__builtin_amdgcn_permlane32_swap)
    unsigned u = __float_as_uint(w);
    auto r = __builtin_amdgcn_permlane32_swap(u, u, false, false);
    float a = __uint_as_float(r[0]), b = __uint_as_float(r[1]);
    return (lane & 32) ? a - b : a + b;
#else
    return bfly_swz<32>(w, lane);
#endif
}

// 6 lane-exchange butterfly stages (masks 1..32) on 4 values (ILP).
__device__ __forceinline__ void lane_fwht6(float& w0, float& w1, float& w2, float& w3, int lane) {
    w0 = bfly_dpp<1>(w0, lane); w1 = bfly_dpp<1>(w1, lane);
    w2 = bfly_dpp<1>(w2, lane); w3 = bfly_dpp<1>(w3, lane);
    w0 = bfly_dpp<2>(w0, lane); w1 = bfly_dpp<2>(w1, lane);
    w2 = bfly_dpp<2>(w2, lane); w3 = bfly_dpp<2>(w3, lane);
    w0 = bfly_swz<4>(w0, lane); w1 = bfly_swz<4>(w1, lane);
    w2 = bfly_swz<4>(w2, lane); w3 = bfly_swz<4>(w3, lane);
    w0 = bfly_swz<8>(w0, lane); w1 = bfly_swz<8>(w1, lane);
    w2 = bfly_swz<8>(w2, lane); w3 = bfly_swz<8>(w3, lane);
    w0 = bfly_pl16(w0, lane);   w1 = bfly_pl16(w1, lane);
    w2 = bfly_pl16(w2, lane);   w3 = bfly_pl16(w3, lane);
    w0 = bfly_pl32(w0, lane);   w1 = bfly_pl32(w1, lane);
    w2 = bfly_pl32(w2, lane);   w3 = bfly_pl32(w3, lane);
}

__device__ __forceinline__ unsigned short f2bf(float f) {
    return (unsigned short)((__float_as_uint(f) + 0x8000u) >> 16);
}
__device__ __forceinline__ float bf2f(unsigned short b) {
    return __uint_as_float(((unsigned)b) << 16);
}

// Single cooperative kernel:
//   Phase A: lo-FWHT (contiguous 256-seg, bf16 out) + jtab/sp table build
//   grid.sync()
//   Phase B: hi-FWHT per (b, 8-lo) tile for all 3 channels + fused scatter
__global__ __launch_bounds__(256) void fused_whcs_k(
        const float* __restrict__ vec, const float* __restrict__ sing,
        const int* __restrict__ perm, unsigned short* __restrict__ mid,
        int* __restrict__ jtab, float* __restrict__ sp,
        float* __restrict__ out) {
    __shared__ unsigned short lds[768 * 10];   // 15360 B
    int t = threadIdx.x;

    // ---------------- Phase A ----------------
    for (int vb = blockIdx.x; vb < A_TOTAL; vb += GRID) {
        if (vb < A_FWHT) {
            int gid  = vb * 256 + t;
            int lane = gid & 63;
            size_t base = (size_t)(gid >> 6) * 256 + lane * 4;
            float4 x = *reinterpret_cast<const float4*>(vec + base);
            float w0 = x.x, w1 = x.y, w2 = x.z, w3 = x.w;
            bfly(w0, w1); bfly(w2, w3);        // lo bit 0
            bfly(w0, w2); bfly(w1, w3);        // lo bit 1
            lane_fwht6(w0, w1, w2, w3, lane);  // lo bits 2..7
            uint2 o;
            o.x = (unsigned)f2bf(w0) | ((unsigned)f2bf(w1) << 16);
            o.y = (unsigned)f2bf(w2) | ((unsigned)f2bf(w3) << 16);
            *reinterpret_cast<uint2*>(mid + base) = o;
        } else {
            int j = (vb - A_FWHT) * 256 + t;
            int n = perm[j];
            if (j < JMAXV) {
                jtab[n] = j;
                F3 s = *reinterpret_cast<const F3*>(sing + 3 * j);
                F3 o;
                o.x = s.x * (1.0f / 256.0f);
                o.y = s.y * (1.0f / 256.0f);
                o.z = s.z * (1.0f / 256.0f);
                *reinterpret_cast<F3*>(sp + 3 * n) = o;
            } else {
                jtab[n] = -1;
            }
        }
    }

    __threadfence();              // device-scope release (cross-XCD L2)
    cg::this_grid().sync();
    __threadfence();              // acquire side

    // ---------------- Phase B ----------------
    int lane = t & 63;
    int w    = t >> 6;
    for (int vb = blockIdx.x; vb < B_TILES; vb += GRID) {
        int b   = vb >> 5;
        int lo0 = (vb & 31) * 8;
        const unsigned short* basep = mid + (size_t)b * (CCH * NTOT);

        // stage: row = c*256+hi, 8 bf16 per row (uint4), pitch 10 shorts
#pragma unroll
        for (int k = 0; k < 3; ++k) {
            int row = k * 256 + t;
            uint4 g = *reinterpret_cast<const uint4*>(basep + (size_t)row * 256 + lo0);
            unsigned short* p = &lds[row * 10];
            *reinterpret_cast<unsigned*>(p + 0) = g.x;
            *reinterpret_cast<unsigned*>(p + 2) = g.y;
            *reinterpret_cast<unsigned*>(p + 4) = g.z;
            *reinterpret_cast<unsigned*>(p + 6) = g.w;
        }
        __syncthreads();

        // 6 (c,lo) columns per wave, read as adjacent bf16-pairs
        float v[6][4];
#pragma unroll
        for (int pr = 0; pr < 3; ++pr) {
            int idx = w * 6 + pr * 2;
            int c   = idx >> 3;
            int lol = idx & 7;
#pragma unroll
            for (int r = 0; r < 4; ++r) {
                unsigned pw = *reinterpret_cast<const unsigned*>(
                    &lds[(c * 256 + r * 64 + lane) * 10 + lol]);
                v[pr * 2    ][r] = __uint_as_float(pw << 16);
                v[pr * 2 + 1][r] = __uint_as_float(pw & 0xFFFF0000u);
            }
        }
        __syncthreads();   // lds about to be reused (scatter layout)

        // hi-FWHT: bits 0..5 lane stages, bits 6,7 in-register
#pragma unroll
        for (int u = 0; u < 6; ++u) {
            lane_fwht6(v[u][0], v[u][1], v[u][2], v[u][3], lane);
            bfly(v[u][0], v[u][1]); bfly(v[u][2], v[u][3]);   // hi bit 6
            bfly(v[u][0], v[u][2]); bfly(v[u][1], v[u][3]);   // hi bit 7
        }

        // transpose back (bf16 pair-packed): lds[hi*26 + idx], pitch 26
#pragma unroll
        for (int pr = 0; pr < 3; ++pr) {
            int idx = w * 6 + pr * 2;
#pragma unroll
            for (int r = 0; r < 4; ++r) {
                int hi = r * 64 + lane;
                unsigned pw = (unsigned)f2bf(v[pr * 2][r]) |
                              ((unsigned)f2bf(v[pr * 2 + 1][r]) << 16);
                *reinterpret_cast<unsigned*>(&lds[hi * 26 + idx]) = pw;
            }
        }
        __syncthreads();

        // scatter: n-contiguous; one 12B store per live n
        float* outb = out + (size_t)b * KK;
#pragma unroll
        for (int k = 0; k < 8; ++k) {
            int p  = k * 256 + t;
            int hi = p >> 3;
            int lo = p & 7;
            int n  = hi * 256 + lo0 + lo;
            int j  = jtab[n];
            if (j >= 0) {
                F3 s = *reinterpret_cast<const F3*>(sp + 3 * n);
                float v0 = bf2f(lds[hi * 26 + 0  + lo]);
                float v1 = bf2f(lds[hi * 26 + 8  + lo]);
                float v2 = bf2f(lds[hi * 26 + 16 + lo]);
                F3 o;
                o.x = s.x * v0; o.y = s.y * v1; o.z = s.z * v2;
                *reinterpret_cast<F3*>(outb + 3 * j) = o;
            }
        }
        __syncthreads();   // protect lds reuse across loop iterations
    }
}

extern "C" void kernel_launch(void* const* d_in, const int* in_sizes, int n_in,
                              void* d_out, int out_size, void* d_ws, size_t ws_size,
                              hipStream_t stream) {
    const float* vec  = (const float*)d_in[0];
    const float* sing = (const float*)d_in[1];
    const int*   perm = (const int*)d_in[2];
    float* out = (float*)d_out;

    int*            jtab = (int*)d_ws;                                 // 256 KB
    float*          sp   = (float*)((char*)d_ws + 262144);             // 768 KB
    unsigned short* mid  = (unsigned short*)((char*)d_ws + 1048576);   // 12.6 MB bf16

    void* args[] = { (void*)&vec, (void*)&sing, (void*)&perm,
                     (void*)&mid, (void*)&jtab, (void*)&sp, (void*)&out };
    hipLaunchCooperativeKernel(reinterpret_cast<void*>(fused_whcs_k),
                               dim3(GRID), dim3(256), args, 0, stream);
}

// Round 5
// 25.946 us; speedup vs baseline: 6.9764x; 6.9764x over previous
//
#include <hip/hip_runtime.h>

// B=32, C=3, IMG=256, N=65536, K=49152, JMAX=16384
#define NTOT 65536
#define CCH 3
#define BB 32
#define KK 49152
#define JMAXV 16384
#define K1_FWHT 768      // (b,c,hi-group) transform blocks
#define K1_TOTAL 1024    // + 256 table-build blocks

struct F3 { float x, y, z; };

__device__ __forceinline__ void bfly(float& a, float& b) {
    float s = a + b, d = a - b; a = s; b = d;
}

// masks 1,2: DPP quad_perm (VALU pipe)
template<int MASK>
__device__ __forceinline__ float bfly_dpp(float w, int lane) {
    constexpr int ctrl = (MASK == 1) ? 0xB1 : 0x4E;  // [1,0,3,2] / [2,3,0,1]
    float p = __uint_as_float((unsigned)__builtin_amdgcn_update_dpp(
        0, (int)__float_as_uint(w), ctrl, 0xF, 0xF, true));
    return (lane & MASK) ? p - w : w + p;
}

// masks 4,8: ds_swizzle via shfl_xor
template<int MASK>
__device__ __forceinline__ float bfly_swz(float w, int lane) {
    float p = __shfl_xor(w, MASK);
    return (lane & MASK) ? p - w : w + p;
}

// mask 16: permlane16_swap (VALU)
__device__ __forceinline__ float bfly_pl16(float w, int lane) {
#if __has_builtin(__builtin_amdgcn_permlane16_swap)
    unsigned u = __float_as_uint(w);
    auto r = __builtin_amdgcn_permlane16_swap(u, u, false, false);
    float a = __uint_as_float(r[0]), b = __uint_as_float(r[1]);
    return (lane & 16) ? a - b : a + b;
#else
    return bfly_swz<16>(w, lane);
#endif
}

// mask 32: permlane32_swap (VALU)
__device__ __forceinline__ float bfly_pl32(float w, int lane) {
#if __has_builtin(__builtin_amdgcn_permlane32_swap)
    unsigned u = __float_as_uint(w);
    auto r = __builtin_amdgcn_permlane32_swap(u, u, false, false);
    float a = __uint_as_float(r[0]), b = __uint_as_float(r[1]);
    return (lane & 32) ? a - b : a + b;
#else
    return bfly_swz<32>(w, lane);
#endif
}

// 6 lane-exchange butterfly stages (masks 1..32) on 4 values (ILP).
__device__ __forceinline__ void lane_fwht6(float& w0, float& w1, float& w2, float& w3, int lane) {
    w0 = bfly_dpp<1>(w0, lane); w1 = bfly_dpp<1>(w1, lane);
    w2 = bfly_dpp<1>(w2, lane); w3 = bfly_dpp<1>(w3, lane);
    w0 = bfly_dpp<2>(w0, lane); w1 = bfly_dpp<2>(w1, lane);
    w2 = bfly_dpp<2>(w2, lane); w3 = bfly_dpp<2>(w3, lane);
    w0 = bfly_swz<4>(w0, lane); w1 = bfly_swz<4>(w1, lane);
    w2 = bfly_swz<4>(w2, lane); w3 = bfly_swz<4>(w3, lane);
    w0 = bfly_swz<8>(w0, lane); w1 = bfly_swz<8>(w1, lane);
    w2 = bfly_swz<8>(w2, lane); w3 = bfly_swz<8>(w3, lane);
    w0 = bfly_pl16(w0, lane);   w1 = bfly_pl16(w1, lane);
    w2 = bfly_pl16(w2, lane);   w3 = bfly_pl16(w3, lane);
    w0 = bfly_pl32(w0, lane);   w1 = bfly_pl32(w1, lane);
    w2 = bfly_pl32(w2, lane);   w3 = bfly_pl32(w3, lane);
}

__device__ __forceinline__ unsigned short f2bf(float f) {
    return (unsigned short)((__float_as_uint(f) + 0x8000u) >> 16);
}

// K1: lo-FWHT of 256-float segments, output TRANSPOSED as bf16:
// mid_t[b][c][lo][hi]. Block = (b*3+c, hi-group of 32). Lane l holds
// lo = r*64+l (bits 0..5 = lane stages, bits 6,7 = in-register).
// Transpose via LDS [256 lo][16 hi-pairs] pitch 17 uints (conflict-free),
// then each thread writes one 64B row chunk (full cache lines).
// Tail blocks build jtab_t[lo*256+hi] = j or -1.
__global__ __launch_bounds__(256) void k1_lo_t(
        const float* __restrict__ vec, unsigned short* __restrict__ midt,
        const int* __restrict__ perm, int* __restrict__ jtabt) {
    __shared__ unsigned lds32[256 * 17];   // 17408 B
    int bx = blockIdx.x, t = threadIdx.x;
    if (bx < K1_FWHT) {
        int rc  = bx >> 3;          // b*3+c
        int hi0 = (bx & 7) * 32;
        const float* src = vec + (size_t)rc * NTOT;
        int lane = t & 63;
        int w    = t >> 6;
#pragma unroll
        for (int k = 0; k < 4; ++k) {      // 4 segment-pairs per wave
            int hi = hi0 + w * 8 + 2 * k;
            const float* p = src + (size_t)hi * 256;
            float a0 = p[lane], a1 = p[64 + lane], a2 = p[128 + lane], a3 = p[192 + lane];
            const float* q = p + 256;
            float b0 = q[lane], b1 = q[64 + lane], b2 = q[128 + lane], b3 = q[192 + lane];

            lane_fwht6(a0, a1, a2, a3, lane);     // lo bits 0..5
            bfly(a0, a1); bfly(a2, a3);           // lo bit 6 (r bit 0)
            bfly(a0, a2); bfly(a1, a3);           // lo bit 7 (r bit 1)
            lane_fwht6(b0, b1, b2, b3, lane);
            bfly(b0, b1); bfly(b2, b3);
            bfly(b0, b2); bfly(b1, b3);

            int pi = w * 4 + k;                   // hi-pair index 0..15
            lds32[(0 * 64 + lane) * 17 + pi] = (unsigned)f2bf(a0) | ((unsigned)f2bf(b0) << 16);
            lds32[(1 * 64 + lane) * 17 + pi] = (unsigned)f2bf(a1) | ((unsigned)f2bf(b1) << 16);
            lds32[(2 * 64 + lane) * 17 + pi] = (unsigned)f2bf(a2) | ((unsigned)f2bf(b2) << 16);
            lds32[(3 * 64 + lane) * 17 + pi] = (unsigned)f2bf(a3) | ((unsigned)f2bf(b3) << 16);
        }
        __syncthreads();

        // thread t: output row lo=t, 32 his = 16 uints = 4x uint4 (64B line)
        unsigned* d32 = reinterpret_cast<unsigned*>(
            midt + (size_t)rc * NTOT + t * 256 + hi0);
#pragma unroll
        for (int q4 = 0; q4 < 4; ++q4) {
            uint4 v;
            v.x = lds32[t * 17 + q4 * 4 + 0];
            v.y = lds32[t * 17 + q4 * 4 + 1];
            v.z = lds32[t * 17 + q4 * 4 + 2];
            v.w = lds32[t * 17 + q4 * 4 + 3];
            reinterpret_cast<uint4*>(d32)[q4] = v;
        }
    } else {
        int j = (bx - K1_FWHT) * 256 + t;
        int n = perm[j];
        jtabt[(n & 255) * 256 + (n >> 8)] = (j < JMAXV) ? j : -1;
    }
}

// K2: hi-FWHT straight from mid_t (coalesced, no LDS), fused scatter.
// Wave = one (b,lo), all 3 channels. Lane l holds hi = {2l,2l+1,128+2l,129+2l}:
// hi bit0 + bit7 in-register, bits 1..6 = lane stages.
__global__ __launch_bounds__(256) void k2_hi_scatter(
        const unsigned short* __restrict__ midt, const int* __restrict__ jtabt,
        const float* __restrict__ sing, float* __restrict__ out) {
    int gid  = blockIdx.x * 256 + threadIdx.x;
    int lane = gid & 63;
    int wid  = gid >> 6;          // 0..8191
    int b    = wid >> 8;
    int lo   = wid & 255;

    float v[3][4];
#pragma unroll
    for (int c = 0; c < 3; ++c) {
        const unsigned* p = reinterpret_cast<const unsigned*>(
            midt + ((size_t)(b * 3 + c)) * NTOT + (size_t)lo * 256);
        unsigned u0 = p[lane];        // his 2l, 2l+1
        unsigned u1 = p[64 + lane];   // his 128+2l, 129+2l
        float w0 = __uint_as_float(u0 << 16);
        float w1 = __uint_as_float(u0 & 0xFFFF0000u);
        float w2 = __uint_as_float(u1 << 16);
        float w3 = __uint_as_float(u1 & 0xFFFF0000u);
        bfly(w0, w1); bfly(w2, w3);        // hi bit 0
        bfly(w0, w2); bfly(w1, w3);        // hi bit 7
        lane_fwht6(w0, w1, w2, w3, lane);  // hi bits 1..6
        v[c][0] = w0; v[c][1] = w1; v[c][2] = w2; v[c][3] = w3;
    }

    const int2* jrow = reinterpret_cast<const int2*>(jtabt + (size_t)lo * 256);
    int2 j01 = jrow[lane];        // j for hi 2l, 2l+1
    int2 j23 = jrow[64 + lane];   // j for hi 128+2l, 129+2l

    float* outb = out + (size_t)b * KK;
#pragma unroll
    for (int i = 0; i < 4; ++i) {
        int j = (i == 0) ? j01.x : (i == 1) ? j01.y : (i == 2) ? j23.x : j23.y;
        if (j >= 0) {
            F3 s = *reinterpret_cast<const F3*>(sing + 3 * j);
            F3 o;
            o.x = (s.x * (1.0f / 256.0f)) * v[0][i];
            o.y = (s.y * (1.0f / 256.0f)) * v[1][i];
            o.z = (s.z * (1.0f / 256.0f)) * v[2][i];
            *reinterpret_cast<F3*>(outb + 3 * j) = o;
        }
    }
}

extern "C" void kernel_launch(void* const* d_in, const int* in_sizes, int n_in,
                              void* d_out, int out_size, void* d_ws, size_t ws_size,
                              hipStream_t stream) {
    const float* vec  = (const float*)d_in[0];
    const float* sing = (const float*)d_in[1];
    const int*   perm = (const int*)d_in[2];
    float* out = (float*)d_out;

    int*            jtabt = (int*)d_ws;                               // 256 KB
    unsigned short* midt  = (unsigned short*)((char*)d_ws + 262144);  // 12.6 MB bf16

    k1_lo_t<<<K1_TOTAL, 256, 0, stream>>>(vec, midt, perm, jtabt);
    k2_hi_scatter<<<BB * 256 / 4, 256, 0, stream>>>(midt, jtabt, sing, out);
}

// Round 6
// 25.283 us; speedup vs baseline: 7.1592x; 1.0262x over previous
//
#include <hip/hip_runtime.h>

// B=32, C=3, IMG=256, N=65536, K=49152, JMAX=16384
#define NTOT 65536
#define CCH 3
#define BB 32
#define KK 49152
#define JMAXV 16384
#define K1_FWHT 768      // (b,c,hi-group) transform blocks
#define K1_TOTAL 1024    // + 256 table-build blocks

struct F3 { float x, y, z; };

__device__ __forceinline__ void bfly(float& a, float& b) {
    float s = a + b, d = a - b; a = s; b = d;
}

// masks 1,2: DPP quad_perm (VALU pipe)
template<int MASK>
__device__ __forceinline__ float bfly_dpp(float w, int lane) {
    constexpr int ctrl = (MASK == 1) ? 0xB1 : 0x4E;  // [1,0,3,2] / [2,3,0,1]
    float p = __uint_as_float((unsigned)__builtin_amdgcn_update_dpp(
        0, (int)__float_as_uint(w), ctrl, 0xF, 0xF, true));
    return (lane & MASK) ? p - w : w + p;
}

// masks 4,8: ds_swizzle via shfl_xor
template<int MASK>
__device__ __forceinline__ float bfly_swz(float w, int lane) {
    float p = __shfl_xor(w, MASK);
    return (lane & MASK) ? p - w : w + p;
}

// mask 16: permlane16_swap (VALU)
__device__ __forceinline__ float bfly_pl16(float w, int lane) {
#if __has_builtin(__builtin_amdgcn_permlane16_swap)
    unsigned u = __float_as_uint(w);
    auto r = __builtin_amdgcn_permlane16_swap(u, u, false, false);
    float a = __uint_as_float(r[0]), b = __uint_as_float(r[1]);
    return (lane & 16) ? a - b : a + b;
#else
    return bfly_swz<16>(w, lane);
#endif
}

// mask 32: permlane32_swap (VALU)
__device__ __forceinline__ float bfly_pl32(float w, int lane) {
#if __has_builtin(__builtin_amdgcn_permlane32_swap)
    unsigned u = __float_as_uint(w);
    auto r = __builtin_amdgcn_permlane32_swap(u, u, false, false);
    float a = __uint_as_float(r[0]), b = __uint_as_float(r[1]);
    return (lane & 32) ? a - b : a + b;
#else
    return bfly_swz<32>(w, lane);
#endif
}

// 6 lane-exchange butterfly stages (masks 1..32) on 4 values (ILP).
__device__ __forceinline__ void lane_fwht6(float& w0, float& w1, float& w2, float& w3, int lane) {
    w0 = bfly_dpp<1>(w0, lane); w1 = bfly_dpp<1>(w1, lane);
    w2 = bfly_dpp<1>(w2, lane); w3 = bfly_dpp<1>(w3, lane);
    w0 = bfly_dpp<2>(w0, lane); w1 = bfly_dpp<2>(w1, lane);
    w2 = bfly_dpp<2>(w2, lane); w3 = bfly_dpp<2>(w3, lane);
    w0 = bfly_swz<4>(w0, lane); w1 = bfly_swz<4>(w1, lane);
    w2 = bfly_swz<4>(w2, lane); w3 = bfly_swz<4>(w3, lane);
    w0 = bfly_swz<8>(w0, lane); w1 = bfly_swz<8>(w1, lane);
    w2 = bfly_swz<8>(w2, lane); w3 = bfly_swz<8>(w3, lane);
    w0 = bfly_pl16(w0, lane);   w1 = bfly_pl16(w1, lane);
    w2 = bfly_pl16(w2, lane);   w3 = bfly_pl16(w3, lane);
    w0 = bfly_pl32(w0, lane);   w1 = bfly_pl32(w1, lane);
    w2 = bfly_pl32(w2, lane);   w3 = bfly_pl32(w3, lane);
}

__device__ __forceinline__ unsigned short f2bf(float f) {
    return (unsigned short)((__float_as_uint(f) + 0x8000u) >> 16);
}

// K1: lo-FWHT of 256-float segments, output TRANSPOSED as bf16
// mid_t[b][c][lo][hi]. Lane l holds lo = 4l+r (r=0..3 in-register: lo bits
// 0,1; lane masks 1..32: lo bits 2..7). Each segment read as ONE float4/lane
// (full 1KB segment per wave-instruction). Two segments (hi, hi+1) per
// iteration, bf16-pair-packed over the hi pair.
// LDS layout [pi][lo] (pi = hi-pair 0..15, 256 uints/row):
//   write: one ds_write_b128/iter at pi*256+4l  (contiguous, conflict-free)
//   read:  16x b32 at pi*256+t, bank = t%32     (2 lanes/bank, free)
// Thread t then stores lo=t's 32 his = 64B (4x uint4 full lines).
// Tail blocks build jtab_t[lo*256+hi] = j or -1.
__global__ __launch_bounds__(256) void k1_lo_t(
        const float* __restrict__ vec, unsigned short* __restrict__ midt,
        const int* __restrict__ perm, int* __restrict__ jtabt) {
    __shared__ unsigned lds32[16 * 256];   // 16 KB
    int bx = blockIdx.x, t = threadIdx.x;
    if (bx < K1_FWHT) {
        int rc  = bx >> 3;          // b*3+c
        int hi0 = (bx & 7) * 32;
        const float* src = vec + (size_t)rc * NTOT;
        int lane = t & 63;
        int w    = t >> 6;
#pragma unroll
        for (int k = 0; k < 4; ++k) {      // 4 segment-pairs per wave
            int hi = hi0 + w * 8 + 2 * k;
            float4 a4 = *reinterpret_cast<const float4*>(src + (size_t)hi * 256 + 4 * lane);
            float4 b4 = *reinterpret_cast<const float4*>(src + (size_t)(hi + 1) * 256 + 4 * lane);
            float a0 = a4.x, a1 = a4.y, a2 = a4.z, a3 = a4.w;
            float b0 = b4.x, b1 = b4.y, b2 = b4.z, b3 = b4.w;

            bfly(a0, a1); bfly(a2, a3);           // lo bit 0
            bfly(a0, a2); bfly(a1, a3);           // lo bit 1
            lane_fwht6(a0, a1, a2, a3, lane);     // lo bits 2..7
            bfly(b0, b1); bfly(b2, b3);
            bfly(b0, b2); bfly(b1, b3);
            lane_fwht6(b0, b1, b2, b3, lane);

            int pi = w * 4 + k;                   // hi-pair index 0..15
            uint4 pk;
            pk.x = (unsigned)f2bf(a0) | ((unsigned)f2bf(b0) << 16);
            pk.y = (unsigned)f2bf(a1) | ((unsigned)f2bf(b1) << 16);
            pk.z = (unsigned)f2bf(a2) | ((unsigned)f2bf(b2) << 16);
            pk.w = (unsigned)f2bf(a3) | ((unsigned)f2bf(b3) << 16);
            *reinterpret_cast<uint4*>(&lds32[pi * 256 + 4 * lane]) = pk;
        }
        __syncthreads();

        // thread t: output row lo=t, 32 his = 16 uints = 4x uint4 (64B line)
        unsigned* d32 = reinterpret_cast<unsigned*>(
            midt + (size_t)rc * NTOT + (size_t)t * 256 + hi0);
#pragma unroll
        for (int q4 = 0; q4 < 4; ++q4) {
            uint4 v;
            v.x = lds32[(q4 * 4 + 0) * 256 + t];
            v.y = lds32[(q4 * 4 + 1) * 256 + t];
            v.z = lds32[(q4 * 4 + 2) * 256 + t];
            v.w = lds32[(q4 * 4 + 3) * 256 + t];
            reinterpret_cast<uint4*>(d32)[q4] = v;
        }
    } else {
        int j = (bx - K1_FWHT) * 256 + t;
        int n = perm[j];
        jtabt[(n & 255) * 256 + (n >> 8)] = (j < JMAXV) ? j : -1;
    }
}

// K2: hi-FWHT straight from mid_t (coalesced, no LDS), fused scatter.
// Wave = one (b,lo), all 3 channels. Lane l holds hi = 4l+r: one uint2/lane
// per channel (full 512B row per wave-instruction); jtab row as one
// int4/lane. hi bits 0,1 in-register, bits 2..7 lane masks.
__global__ __launch_bounds__(256) void k2_hi_scatter(
        const unsigned short* __restrict__ midt, const int* __restrict__ jtabt,
        const float* __restrict__ sing, float* __restrict__ out) {
    int gid  = blockIdx.x * 256 + threadIdx.x;
    int lane = gid & 63;
    int wid  = gid >> 6;          // 0..8191
    int b    = wid >> 8;
    int lo   = wid & 255;

    float v[3][4];
#pragma unroll
    for (int c = 0; c < 3; ++c) {
        const uint2* p = reinterpret_cast<const uint2*>(
            midt + ((size_t)(b * 3 + c)) * NTOT + (size_t)lo * 256);
        uint2 u = p[lane];            // his 4l..4l+3 (bf16-packed)
        float w0 = __uint_as_float(u.x << 16);
        float w1 = __uint_as_float(u.x & 0xFFFF0000u);
        float w2 = __uint_as_float(u.y << 16);
        float w3 = __uint_as_float(u.y & 0xFFFF0000u);
        bfly(w0, w1); bfly(w2, w3);        // hi bit 0
        bfly(w0, w2); bfly(w1, w3);        // hi bit 1
        lane_fwht6(w0, w1, w2, w3, lane);  // hi bits 2..7
        v[c][0] = w0; v[c][1] = w1; v[c][2] = w2; v[c][3] = w3;
    }

    int4 jq = reinterpret_cast<const int4*>(jtabt + (size_t)lo * 256)[lane];
    int jj[4] = { jq.x, jq.y, jq.z, jq.w };   // j for hi = 4l+0..3

    float* outb = out + (size_t)b * KK;
#pragma unroll
    for (int i = 0; i < 4; ++i) {
        int j = jj[i];
        if (j >= 0) {
            F3 s = *reinterpret_cast<const F3*>(sing + 3 * j);
            F3 o;
            o.x = (s.x * (1.0f / 256.0f)) * v[0][i];
            o.y = (s.y * (1.0f / 256.0f)) * v[1][i];
            o.z = (s.z * (1.0f / 256.0f)) * v[2][i];
            *reinterpret_cast<F3*>(outb + 3 * j) = o;
        }
    }
}

extern "C" void kernel_launch(void* const* d_in, const int* in_sizes, int n_in,
                              void* d_out, int out_size, void* d_ws, size_t ws_size,
                              hipStream_t stream) {
    const float* vec  = (const float*)d_in[0];
    const float* sing = (const float*)d_in[1];
    const int*   perm = (const int*)d_in[2];
    float* out = (float*)d_out;

    int*            jtabt = (int*)d_ws;                               // 256 KB
    unsigned short* midt  = (unsigned short*)((char*)d_ws + 262144);  // 12.6 MB bf16

    k1_lo_t<<<K1_TOTAL, 256, 0, stream>>>(vec, midt, perm, jtabt);
    k2_hi_scatter<<<BB * 256 / 4, 256, 0, stream>>>(midt, jtabt, sing, out);
}